// Round 12
// baseline (1158.806 us; speedup 1.0000x reference)
//
#include <hip/hip_runtime.h>
#include <hip/hip_bf16.h>
#include <math.h>

#define E_DIM 1024
#define H_NUM 16
#define D_DIM 64
#define F_DIM 4096
#define L_NUM 4
#define B_NUM 2
#define S_LEN 1024
#define V_DIM 50257
#define M_TOK 2048   // B*S

typedef __attribute__((ext_vector_type(8))) short s8v;    // 8 bf16 (4 VGPRs)
typedef __attribute__((ext_vector_type(4))) float f4v;    // 4 fp32

static __device__ __forceinline__ float bf2f(unsigned short u) {
    union { unsigned int i; float f; } c; c.i = ((unsigned int)u) << 16; return c.f;
}
static __device__ __forceinline__ unsigned short f2bf(float f) {
    union { float f; unsigned int i; } c; c.f = f;
    unsigned int r = c.i + 0x7FFFu + ((c.i >> 16) & 1u);
    return (unsigned short)(r >> 16);
}

// async global->LDS, 16B per lane; dest is wave-uniform base + lane*16
static __device__ __forceinline__ void gload16(const ushort* g, ushort* l) {
    __builtin_amdgcn_global_load_lds(
        (const __attribute__((address_space(1))) unsigned int*)g,
        (__attribute__((address_space(3))) unsigned int*)l, 16, 0, 0);
}

// ---------------------------------------------------------------- embedding
__global__ void embed_kernel(const int* __restrict__ idx,
                             const float* __restrict__ tok,
                             const float* __restrict__ pos,
                             float* __restrict__ x) {
    int row = blockIdx.x;
    int s = row & (S_LEN - 1);
    int t = idx[row];
    const float* te = tok + (size_t)t * E_DIM;
    const float* pe = pos + (size_t)s * E_DIM;
    float* xr = x + (size_t)row * E_DIM;
    int c = threadIdx.x * 4;
    float4 a = *(const float4*)(te + c);
    float4 p = *(const float4*)(pe + c);
    float4 o; o.x = a.x + p.x; o.y = a.y + p.y; o.z = a.z + p.z; o.w = a.w + p.w;
    *(float4*)(xr + c) = o;
}

// ---------------------------------------------------------------- layernorm
__global__ void ln_kernel(const float* __restrict__ x,
                          const float* __restrict__ w,
                          const float* __restrict__ b,
                          ushort* __restrict__ out) {
    int row = blockIdx.x;
    const float* xr = x + (size_t)row * E_DIM;
    int tid = threadIdx.x;
    float4 v = *(const float4*)(xr + tid * 4);
    float s  = v.x + v.y + v.z + v.w;
    float s2 = v.x*v.x + v.y*v.y + v.z*v.z + v.w*v.w;
    #pragma unroll
    for (int m = 32; m >= 1; m >>= 1) {
        s  += __shfl_xor(s,  m, 64);
        s2 += __shfl_xor(s2, m, 64);
    }
    __shared__ float red[8];
    int wid = tid >> 6;
    if ((tid & 63) == 0) { red[wid] = s; red[wid + 4] = s2; }
    __syncthreads();
    s  = red[0] + red[1] + red[2] + red[3];
    s2 = red[4] + red[5] + red[6] + red[7];
    float mu  = s * (1.0f / E_DIM);
    float var = s2 * (1.0f / E_DIM) - mu * mu;
    float rs  = rsqrtf(var + 1e-5f);
    float4 wv = *(const float4*)(w + tid * 4);
    float4 bv = *(const float4*)(b + tid * 4);
    ushort4 o;
    o.x = f2bf((v.x - mu) * rs * wv.x + bv.x);
    o.y = f2bf((v.y - mu) * rs * wv.y + bv.y);
    o.z = f2bf((v.z - mu) * rs * wv.z + bv.z);
    o.w = f2bf((v.w - mu) * rs * wv.w + bv.w);
    *(ushort4*)(out + (size_t)row * E_DIM + tid * 4) = o;
}

// ---------------------------------------------------------------- weight prep
static __device__ __forceinline__ void tconv_body(
    const float* __restrict__ in, ushort* __restrict__ out, int K, int N, int bx, int by)
{
    __shared__ ushort t[64][72];
    int n0 = bx * 64, k0 = by * 64;
    int tid = threadIdx.x;
    int r = tid >> 4, c = (tid & 15) * 4;
    #pragma unroll
    for (int it = 0; it < 4; ++it) {
        int kl = it * 16 + r;
        float4 v = *(const float4*)(in + (size_t)(k0 + kl) * N + n0 + c);
        t[kl][c]   = f2bf(v.x); t[kl][c+1] = f2bf(v.y);
        t[kl][c+2] = f2bf(v.z); t[kl][c+3] = f2bf(v.w);
    }
    __syncthreads();
    int nl = tid >> 2, k8 = (tid & 3) * 16;
    s8v o0, o1;
    #pragma unroll
    for (int j = 0; j < 8; ++j) o0[j] = (short)t[k8 + j][nl];
    #pragma unroll
    for (int j = 0; j < 8; ++j) o1[j] = (short)t[k8 + 8 + j][nl];
    *(s8v*)(out + (size_t)(n0 + nl) * K + k0 + k8)     = o0;
    *(s8v*)(out + (size_t)(n0 + nl) * K + k0 + k8 + 8) = o1;
}

__global__ __launch_bounds__(256) void tconv_kernel(const float* __restrict__ in,
                                                    ushort* __restrict__ out, int K, int N) {
    tconv_body(in, out, K, N, blockIdx.x, blockIdx.y);
}

__global__ __launch_bounds__(256) void tconv_qkvo_all(
    const float* __restrict__ Wq, const float* __restrict__ Wk,
    const float* __restrict__ Wv, const float* __restrict__ Wo,
    ushort* __restrict__ out)
{
    int z = blockIdx.z, l = z >> 2, w = z & 3;
    const float* in = (w == 0 ? Wq : w == 1 ? Wk : w == 2 ? Wv : Wo)
                      + (size_t)l * E_DIM * E_DIM;
    tconv_body(in, out + (size_t)z * E_DIM * E_DIM, E_DIM, E_DIM, blockIdx.x, blockIdx.y);
}

__global__ __launch_bounds__(256) void tconv_w_all(
    const float* __restrict__ W, ushort* __restrict__ out, int K, int N)
{
    int l = blockIdx.z;
    tconv_body(W + (size_t)l * K * N, out + (size_t)l * K * N, K, N, blockIdx.x, blockIdx.y);
}

__global__ void conv_kernel(const float* __restrict__ in, ushort* __restrict__ out, int n) {
    int i = (blockIdx.x * 256 + threadIdx.x) * 8;
    if (i + 8 <= n) {
        float4 a = *(const float4*)(in + i);
        float4 b = *(const float4*)(in + i + 4);
        s8v o;
        o[0]=(short)f2bf(a.x); o[1]=(short)f2bf(a.y); o[2]=(short)f2bf(a.z); o[3]=(short)f2bf(a.w);
        o[4]=(short)f2bf(b.x); o[5]=(short)f2bf(b.y); o[6]=(short)f2bf(b.z); o[7]=(short)f2bf(b.w);
        *(s8v*)(out + i) = o;
    }
}

// ---------------------------------------------------------------- MFMA flash attention (split-KV)
// qt remap (R10-proven): bid<256 -> qt 15..8, bid>=256 -> qt 0..7.
// CU pairs (bid, bid+256) => (qt, 15-qt): round-sums all equal 9 (was 6..12).
#define KSTR 72
#define VSTR 144
__global__ __launch_bounds__(512, 4) void attn_mfma_kernel(
    const ushort* __restrict__ qg, const ushort* __restrict__ kg,
    const ushort* __restrict__ vg, ushort* __restrict__ yg)
{
    __shared__ ushort smem[27648];
    ushort (*Ks)[KSTR] = (ushort(*)[KSTR])smem;
    ushort (*Vt)[VSTR] = (ushort(*)[VSTR])(smem + 128 * KSTR);
    ushort (*Ps)[16][KSTR] = (ushort(*)[16][KSTR])(smem + 128 * KSTR + 64 * VSTR);
    float* mb = (float*)smem;

    int tid = threadIdx.x;
    int wid = tid >> 6, lane = tid & 63;
    int c = lane & 15, g = lane >> 4;
    int grp = wid >> 2, ws = wid & 3;

    int bid = blockIdx.x;
    int head = bid & 31;
    int qt = (bid < 256) ? (15 - (bid >> 5)) : ((bid >> 5) - 8);
    int b = head >> 4, h = head & 15;
    int qw = qt * 64 + ws * 16;
    size_t base = (size_t)b * S_LEN * E_DIM + (size_t)(h * D_DIM);

    s8v qf[2];
    #pragma unroll
    for (int ks = 0; ks < 2; ++ks)
        qf[ks] = *(const s8v*)(qg + base + (size_t)(qw + c) * E_DIM + ks * 32 + g * 8);

    f4v o[4];
    #pragma unroll
    for (int dt = 0; dt < 4; ++dt) o[dt] = (f4v){0.f, 0.f, 0.f, 0.f};
    float m[4], lsum[4];
    #pragma unroll
    for (int j = 0; j < 4; ++j) { m[j] = -1e30f; lsum[j] = 0.f; }

    int nr = (qt >> 1) + 1;
    for (int r = 0; r < nr; ++r) {
        int t0 = r * 128;
        #pragma unroll
        for (int it = 0; it < 2; ++it) {
            int ch = tid + it * 512;
            int tr = ch >> 3, dc = (ch & 7) << 3;
            s8v kv = *(const s8v*)(kg + base + (size_t)(t0 + tr) * E_DIM + dc);
            *(s8v*)(&Ks[tr][dc]) = kv;
            s8v vv = *(const s8v*)(vg + base + (size_t)(t0 + tr) * E_DIM + dc);
            int tsw = tr ^ dc;
            #pragma unroll
            for (int j = 0; j < 8; ++j)
                Vt[dc + j][tsw] = (ushort)vv[j];
        }
        __syncthreads();

        int myt = r * 2 + grp;
        if (myt <= qt) {
            int toff = grp * 64;
            f4v s4[4];
            #pragma unroll
            for (int tj = 0; tj < 4; ++tj) {
                s4[tj] = (f4v){0.f, 0.f, 0.f, 0.f};
                #pragma unroll
                for (int ks = 0; ks < 2; ++ks) {
                    s8v kf = *(const s8v*)(&Ks[toff + tj * 16 + c][ks * 32 + g * 8]);
                    s4[tj] = __builtin_amdgcn_mfma_f32_16x16x32_bf16(qf[ks], kf, s4[tj], 0, 0, 0);
                }
            }

            bool diag = (myt == qt);
            float sc[4][4], pm[4];
            #pragma unroll
            for (int j = 0; j < 4; ++j) pm[j] = -1e30f;
            #pragma unroll
            for (int tj = 0; tj < 4; ++tj)
                #pragma unroll
                for (int j = 0; j < 4; ++j) {
                    float val = s4[tj][j] * 0.125f;
                    if (diag) {
                        int t_loc = tj * 16 + c;
                        int q_loc = ws * 16 + 4 * g + j;
                        if (t_loc > q_loc) val = -1e30f;
                    }
                    sc[tj][j] = val;
                    pm[j] = fmaxf(pm[j], val);
                }
            #pragma unroll
            for (int msk = 1; msk <= 8; msk <<= 1)
                #pragma unroll
                for (int j = 0; j < 4; ++j)
                    pm[j] = fmaxf(pm[j], __shfl_xor(pm[j], msk, 64));
            float rs[4], corr[4];
            #pragma unroll
            for (int j = 0; j < 4; ++j) {
                float nm = fmaxf(m[j], pm[j]);
                corr[j] = __expf(m[j] - nm);
                m[j] = nm;
                rs[j] = 0.f;
            }
            #pragma unroll
            for (int tj = 0; tj < 4; ++tj)
                #pragma unroll
                for (int j = 0; j < 4; ++j) {
                    float p = __expf(sc[tj][j] - m[j]);
                    rs[j] += p;
                    Ps[wid][4 * g + j][(tj * 16 + c) ^ (g << 3)] = f2bf(p);
                }
            #pragma unroll
            for (int msk = 1; msk <= 8; msk <<= 1)
                #pragma unroll
                for (int j = 0; j < 4; ++j)
                    rs[j] += __shfl_xor(rs[j], msk, 64);
            #pragma unroll
            for (int j = 0; j < 4; ++j) lsum[j] = lsum[j] * corr[j] + rs[j];
            #pragma unroll
            for (int dt = 0; dt < 4; ++dt)
                #pragma unroll
                for (int j = 0; j < 4; ++j) o[dt][j] *= corr[j];

            #pragma unroll
            for (int ks = 0; ks < 2; ++ks) {
                int blk = g + 4 * ks;
                int pblk = blk ^ (c >> 2);
                s8v pa = *(const s8v*)(&Ps[wid][c][pblk << 3]);
                int tb = grp * 8 + blk;
                #pragma unroll
                for (int dt = 0; dt < 4; ++dt) {
                    int d = dt * 16 + c;
                    int vblk = tb ^ ((d >> 3) & 7);
                    s8v vb = *(const s8v*)(&Vt[d][vblk << 3]);
                    o[dt] = __builtin_amdgcn_mfma_f32_16x16x32_bf16(pa, vb, o[dt], 0, 0, 0);
                }
            }
        }
        __syncthreads();
    }

    if (grp == 1) {
        float* dst = mb + (ws * 64 + lane) * 25;
        #pragma unroll
        for (int j = 0; j < 4; ++j) { dst[j] = m[j]; dst[4 + j] = lsum[j]; }
        #pragma unroll
        for (int dt = 0; dt < 4; ++dt)
            #pragma unroll
            for (int j = 0; j < 4; ++j) dst[8 + dt * 4 + j] = o[dt][j];
    }
    __syncthreads();
    if (grp == 0) {
        const float* src = mb + (ws * 64 + lane) * 25;
        float sA[4], sB[4];
        #pragma unroll
        for (int j = 0; j < 4; ++j) {
            float mB = src[j], lB = src[4 + j];
            float mN = fmaxf(m[j], mB);
            sA[j] = __expf(m[j] - mN);
            sB[j] = __expf(mB - mN);
            lsum[j] = lsum[j] * sA[j] + lB * sB[j];
        }
        float inv[4];
        #pragma unroll
        for (int j = 0; j < 4; ++j) inv[j] = 1.f / lsum[j];
        #pragma unroll
        for (int dt = 0; dt < 4; ++dt)
            #pragma unroll
            for (int j = 0; j < 4; ++j) {
                float ov = o[dt][j] * sA[j] + src[8 + dt * 4 + j] * sB[j];
                yg[base + (size_t)(qw + 4 * g + j) * E_DIM + dt * 16 + c] = f2bf(ov * inv[j]);
            }
    }
}

// ---------------------------------------------------------------- bf16 GEMM 128x128 (proven)
template<int EPI>
static __device__ __forceinline__ void gemm_bb_body(
    const ushort* __restrict__ A, const ushort* __restrict__ B,
    const float* __restrict__ bias, const float* __restrict__ res,
    float* __restrict__ outF, ushort* __restrict__ outB,
    int Ndim, int Kdim, int m0, int n0, int nRows)
{
    __shared__ ushort As[128 * 64];
    __shared__ ushort Bs[128 * 64];
    int tid = threadIdx.x;
    int wid = tid >> 6, lane = tid & 63;
    int wr = wid >> 1, wc = wid & 1;
    int fr = lane & 15, fq = lane >> 4;
    int lr = lane >> 3, ls = lane & 7;

    f4v acc[4][4];
    #pragma unroll
    for (int mi = 0; mi < 4; ++mi)
        #pragma unroll
        for (int ni = 0; ni < 4; ++ni)
            acc[mi][ni] = (f4v){0.f, 0.f, 0.f, 0.f};

    for (int k0 = 0; k0 < Kdim; k0 += 64) {
        #pragma unroll
        for (int it = 0; it < 4; ++it) {
            int r = wid * 32 + it * 8 + lr;
            int ss = ls ^ (r & 7);
            gload16(A + (size_t)(m0 + r) * Kdim + k0 + ss * 8,
                    As + r * 64 - lr * 64 - ls * 8);
        }
        #pragma unroll
        for (int it = 0; it < 4; ++it) {
            int r = wid * 32 + it * 8 + lr;
            int ss = ls ^ (r & 7);
            int br = n0 + r; if (br >= nRows) br = nRows - 1;
            gload16(B + (size_t)br * Kdim + k0 + ss * 8,
                    Bs + r * 64 - lr * 64 - ls * 8);
        }
        __syncthreads();
        #pragma unroll
        for (int ks = 0; ks < 2; ++ks) {
            s8v af[4], bfv[4];
            #pragma unroll
            for (int mi = 0; mi < 4; ++mi) {
                int Ra = wr * 64 + mi * 16 + fr;
                int Sa = (ks * 4 + fq) ^ (fr & 7);
                af[mi] = *(const s8v*)(As + Ra * 64 + Sa * 8);
            }
            #pragma unroll
            for (int ni = 0; ni < 4; ++ni) {
                int Rb = wc * 64 + ni * 16 + fr;
                int Sb = (ks * 4 + fq) ^ (fr & 7);
                bfv[ni] = *(const s8v*)(Bs + Rb * 64 + Sb * 8);
            }
            #pragma unroll
            for (int mi = 0; mi < 4; ++mi)
                #pragma unroll
                for (int ni = 0; ni < 4; ++ni)
                    acc[mi][ni] = __builtin_amdgcn_mfma_f32_16x16x32_bf16(
                        af[mi], bfv[ni], acc[mi][ni], 0, 0, 0);
        }
        __syncthreads();
    }

    #pragma unroll
    for (int mi = 0; mi < 4; ++mi) {
        int row = m0 + wr * 64 + mi * 16 + fq * 4;
        #pragma unroll
        for (int ni = 0; ni < 4; ++ni) {
            int col = n0 + wc * 64 + ni * 16 + fr;
            float bv = 0.f;
            if (EPI == 0 || EPI == 1 || EPI == 2) bv = bias[col];
            #pragma unroll
            for (int j = 0; j < 4; ++j) {
                float val = acc[mi][ni][j] + bv;
                size_t off = (size_t)(row + j) * Ndim + col;
                if (EPI == 0) {
                    outB[off] = f2bf(val);
                } else if (EPI == 1) {
                    outF[off] = res[off] + val;
                } else if (EPI == 2) {
                    val = 0.5f * val * (1.f + erff(val * 0.70710678118654752f));
                    outB[off] = f2bf(val);
                } else {
                    if (col < Ndim) outF[off] = val;
                }
            }
        }
    }
}

template<int EPI>
__global__ __launch_bounds__(256) void gemm_bb_kernel(
    const ushort* __restrict__ A, const ushort* __restrict__ B,
    const float* __restrict__ bias, const float* __restrict__ res,
    float* __restrict__ outF, ushort* __restrict__ outB,
    int Ndim, int Kdim, int nRows)
{
    int x = blockIdx.x & 7, i = blockIdx.x >> 3;
    int mb = x * 2 + (i & 1), nb = i >> 1;
    gemm_bb_body<EPI>(A, B, bias, res, outF, outB, Ndim, Kdim, mb * 128, nb * 128, nRows);
}

__global__ __launch_bounds__(256) void gemm_qkv_bb_kernel(
    const ushort* __restrict__ A,
    const ushort* __restrict__ Bq, const ushort* __restrict__ Bk, const ushort* __restrict__ Bv,
    const float* __restrict__ bq, const float* __restrict__ bk, const float* __restrict__ bv,
    ushort* __restrict__ oq, ushort* __restrict__ ok, ushort* __restrict__ ov)
{
    int x = blockIdx.x & 7, i = blockIdx.x >> 3;
    int sel = i >> 4, j = i & 15;
    int mb = x * 2 + (j & 1), nb = j >> 1;
    const ushort* B   = (sel == 0) ? Bq : (sel == 1) ? Bk : Bv;
    const float* bias = (sel == 0) ? bq : (sel == 1) ? bk : bv;
    ushort* o         = (sel == 0) ? oq : (sel == 1) ? ok : ov;
    gemm_bb_body<0>(A, B, bias, nullptr, nullptr, o, E_DIM, E_DIM, mb * 128, nb * 128, E_DIM);
}

// ---------------------------------------------------------------- bf16 GEMM 64x128
template<int EPI>
static __device__ __forceinline__ void gemm64_body(
    const ushort* __restrict__ A, const ushort* __restrict__ B,
    const float* __restrict__ bias, const float* __restrict__ res,
    float* __restrict__ outF, ushort* __restrict__ outB,
    int Ndim, int Kdim, int m0, int n0)
{
    __shared__ ushort As[64 * 64];
    __shared__ ushort Bs[128 * 64];
    int tid = threadIdx.x;
    int wid = tid >> 6, lane = tid & 63;
    int fr = lane & 15, fq = lane >> 4;
    int lr = lane >> 3, ls = lane & 7;

    f4v acc[4][2];
    #pragma unroll
    for (int mi = 0; mi < 4; ++mi)
        #pragma unroll
        for (int ni = 0; ni < 2; ++ni)
            acc[mi][ni] = (f4v){0.f, 0.f, 0.f, 0.f};

    for (int k0 = 0; k0 < Kdim; k0 += 64) {
        #pragma unroll
        for (int it = 0; it < 2; ++it) {
            int r = wid * 16 + it * 8 + lr;
            int ss = ls ^ (r & 7);
            gload16(A + (size_t)(m0 + r) * Kdim + k0 + ss * 8,
                    As + r * 64 - lr * 64 - ls * 8);
        }
        #pragma unroll
        for (int it = 0; it < 4; ++it) {
            int r = wid * 32 + it * 8 + lr;
            int ss = ls ^ (r & 7);
            gload16(B + (size_t)(n0 + r) * Kdim + k0 + ss * 8,
                    Bs + r * 64 - lr * 64 - ls * 8);
        }
        __syncthreads();
        #pragma unroll
        for (int ks = 0; ks < 2; ++ks) {
            s8v af[4], bfv[2];
            #pragma unroll
            for (int mi = 0; mi < 4; ++mi) {
                int Ra = mi * 16 + fr;
                int Sa = (ks * 4 + fq) ^ (fr & 7);
                af[mi] = *(const s8v*)(As + Ra * 64 + Sa * 8);
            }
            #pragma unroll
            for (int ni = 0; ni < 2; ++ni) {
                int Rb = wid * 32 + ni * 16 + fr;
                int Sb = (ks * 4 + fq) ^ (fr & 7);
                bfv[ni] = *(const s8v*)(Bs + Rb * 64 + Sb * 8);
            }
            #pragma unroll
            for (int mi = 0; mi < 4; ++mi)
                #pragma unroll
                for (int ni = 0; ni < 2; ++ni)
                    acc[mi][ni] = __builtin_amdgcn_mfma_f32_16x16x32_bf16(
                        af[mi], bfv[ni], acc[mi][ni], 0, 0, 0);
        }
        __syncthreads();
    }

    #pragma unroll
    for (int mi = 0; mi < 4; ++mi) {
        int row = m0 + mi * 16 + fq * 4;
        #pragma unroll
        for (int ni = 0; ni < 2; ++ni) {
            int col = n0 + wid * 32 + ni * 16 + fr;
            float bv = bias[col];
            #pragma unroll
            for (int j = 0; j < 4; ++j) {
                float val = acc[mi][ni][j] + bv;
                size_t off = (size_t)(row + j) * Ndim + col;
                if (EPI == 0) {
                    outB[off] = f2bf(val);
                } else {
                    outF[off] = res[off] + val;
                }
            }
        }
    }
}

template<int EPI>
__global__ __launch_bounds__(256) void gemm64_kernel(
    const ushort* __restrict__ A, const ushort* __restrict__ B,
    const float* __restrict__ bias, const float* __restrict__ res,
    float* __restrict__ outF, ushort* __restrict__ outB,
    int Ndim, int Kdim)
{
    int x = blockIdx.x & 7, i = blockIdx.x >> 3;
    int mb = x * 4 + (i & 3), nb = i >> 2;
    gemm64_body<EPI>(A, B, bias, res, outF, outB, Ndim, Kdim, mb * 64, nb * 128);
}

__global__ __launch_bounds__(256) void gemm64_qkv_kernel(
    const ushort* __restrict__ A, const ushort* __restrict__ Wall,
    const float* __restrict__ bq, const float* __restrict__ bk, const float* __restrict__ bv,
    ushort* __restrict__ oq, ushort* __restrict__ ok, ushort* __restrict__ ov)
{
    int x = blockIdx.x & 7, i = blockIdx.x >> 3;
    int sel = i >> 5, j = i & 31;
    int mb = x * 4 + (j & 3), nb = j >> 2;
    const ushort* B   = Wall + (size_t)sel * E_DIM * E_DIM;
    const float* bias = (sel == 0) ? bq : (sel == 1) ? bk : bv;
    ushort* o         = (sel == 0) ? oq : (sel == 1) ? ok : ov;
    gemm64_body<0>(A, B, bias, nullptr, nullptr, o, E_DIM, E_DIM, mb * 64, nb * 128);
}

// ---------------------------------------------------------------- head GEMM 256x128, 8 waves
// R11-proven body. NEW block mapping: XCD x owns nb slice [50x, 50x+50), mb-fast
// within: the 8 blocks sharing a B panel run concurrently on ONE XCD -> 1 HBM
// fetch + 7 L2 hits (no cross-XCD L3 alignment needed). A (4MB) stays L3-resident.
// Grid 3200 = 8 x 400; blocks with nb >= 393 return.
__global__ __launch_bounds__(512) void gemm_head_kernel(
    const ushort* __restrict__ A, const ushort* __restrict__ B,
    float* __restrict__ outF, int Ndim, int Kdim, int nRows)
{
    __shared__ ushort As[256 * 64];
    __shared__ ushort Bs[128 * 64];
    int tid = threadIdx.x;
    int wid = tid >> 6, lane = tid & 63;
    int wr = wid >> 1, wc = wid & 1;         // 4M x 2N wave grid
    int fr = lane & 15, fq = lane >> 4;
    int lr = lane >> 3, ls = lane & 7;

    int xcd = blockIdx.x & 7, i = blockIdx.x >> 3;   // i 0..399
    int nb = xcd * 50 + (i >> 3);
    int mb = i & 7;
    if (nb >= 393) return;
    int m0 = mb * 256, n0 = nb * 128;

    f4v acc[4][4];
    #pragma unroll
    for (int mi = 0; mi < 4; ++mi)
        #pragma unroll
        for (int ni = 0; ni < 4; ++ni)
            acc[mi][ni] = (f4v){0.f, 0.f, 0.f, 0.f};

    for (int k0 = 0; k0 < Kdim; k0 += 64) {
        #pragma unroll
        for (int it = 0; it < 4; ++it) {
            int r = wid * 32 + it * 8 + lr;
            int ss = ls ^ (r & 7);
            gload16(A + (size_t)(m0 + r) * Kdim + k0 + ss * 8,
                    As + r * 64 - lr * 64 - ls * 8);
        }
        #pragma unroll
        for (int it = 0; it < 2; ++it) {
            int r = wid * 16 + it * 8 + lr;
            int ss = ls ^ (r & 7);
            int br = n0 + r; if (br >= nRows) br = nRows - 1;
            gload16(B + (size_t)br * Kdim + k0 + ss * 8,
                    Bs + r * 64 - lr * 64 - ls * 8);
        }
        __syncthreads();
        #pragma unroll
        for (int ks = 0; ks < 2; ++ks) {
            s8v af[4], bfv[4];
            #pragma unroll
            for (int mi = 0; mi < 4; ++mi) {
                int Ra = wr * 64 + mi * 16 + fr;
                int Sa = (ks * 4 + fq) ^ (fr & 7);
                af[mi] = *(const s8v*)(As + Ra * 64 + Sa * 8);
            }
            #pragma unroll
            for (int ni = 0; ni < 4; ++ni) {
                int Rb = wc * 64 + ni * 16 + fr;
                int Sb = (ks * 4 + fq) ^ (fr & 7);
                bfv[ni] = *(const s8v*)(Bs + Rb * 64 + Sb * 8);
            }
            #pragma unroll
            for (int mi = 0; mi < 4; ++mi)
                #pragma unroll
                for (int ni = 0; ni < 4; ++ni)
                    acc[mi][ni] = __builtin_amdgcn_mfma_f32_16x16x32_bf16(
                        af[mi], bfv[ni], acc[mi][ni], 0, 0, 0);
        }
        __syncthreads();
    }

    #pragma unroll
    for (int mi = 0; mi < 4; ++mi) {
        int row = m0 + wr * 64 + mi * 16 + fq * 4;
        #pragma unroll
        for (int ni = 0; ni < 4; ++ni) {
            int col = n0 + wc * 64 + ni * 16 + fr;
            if (col < Ndim) {
                #pragma unroll
                for (int j = 0; j < 4; ++j)
                    outF[(size_t)(row + j) * Ndim + col] = acc[mi][ni][j];
            }
        }
    }
}

// ---------------------------------------------------------------- launch
extern "C" void kernel_launch(void* const* d_in, const int* in_sizes, int n_in,
                              void* d_out, int out_size, void* d_ws, size_t ws_size,
                              hipStream_t stream) {
    (void)in_sizes; (void)n_in; (void)out_size;
    const int*   idx  = (const int*)d_in[0];
    const float* tok  = (const float*)d_in[1];
    const float* pos  = (const float*)d_in[2];
    const float* ln1w = (const float*)d_in[3];
    const float* ln1b = (const float*)d_in[4];
    const float* Wq   = (const float*)d_in[5];
    const float* bq   = (const float*)d_in[6];
    const float* Wk   = (const float*)d_in[7];
    const float* bk   = (const float*)d_in[8];
    const float* Wv   = (const float*)d_in[9];
    const float* bv   = (const float*)d_in[10];
    const float* Wo   = (const float*)d_in[11];
    const float* bo   = (const float*)d_in[12];
    const float* ln2w = (const float*)d_in[13];
    const float* ln2b = (const float*)d_in[14];
    const float* W1   = (const float*)d_in[15];
    const float* b1   = (const float*)d_in[16];
    const float* W2   = (const float*)d_in[17];
    const float* b2   = (const float*)d_in[18];
    const float* lnfw = (const float*)d_in[19];
    const float* lnfb = (const float*)d_in[20];
    const float* headW= (const float*)d_in[21];
    float* out = (float*)d_out;

    char* ws = (char*)d_ws;
    float*  x  = (float*)(ws);                              // 8 MB
    ushort* h  = (ushort*)(ws + 8u  * 1024 * 1024);         // 4 MB
    ushort* qb = (ushort*)(ws + 12u * 1024 * 1024);
    ushort* kb = (ushort*)(ws + 16u * 1024 * 1024);
    ushort* vb = (ushort*)(ws + 20u * 1024 * 1024);
    ushort* yb = (ushort*)(ws + 24u * 1024 * 1024);
    ushort* ub = (ushort*)(ws + 28u * 1024 * 1024);         // 16 MB
    // mid tier: per-layer reuse buffers
    ushort* wqb = (ushort*)(ws + 44u * 1024 * 1024);
    ushort* wkb = (ushort*)(ws + 46u * 1024 * 1024);
    ushort* wvb = (ushort*)(ws + 48u * 1024 * 1024);
    ushort* wob = (ushort*)(ws + 50u * 1024 * 1024);
    ushort* w1b = (ushort*)(ws + 52u * 1024 * 1024);
    ushort* w2b = (ushort*)(ws + 60u * 1024 * 1024);
    ushort* hdbM = (ushort*)(ws + 68u * 1024 * 1024);       // mid-tier head (98.2 MB)
    // huge tier: all weights upfront
    ushort* wall  = (ushort*)(ws + 44u  * 1024 * 1024);     // 32 MB
    ushort* w1all = (ushort*)(ws + 76u  * 1024 * 1024);     // 32 MB
    ushort* w2all = (ushort*)(ws + 108u * 1024 * 1024);     // 32 MB
    ushort* hdbH  = (ushort*)(ws + 140u * 1024 * 1024);     // 98.2 MB

    size_t headB = (size_t)V_DIM * E_DIM * 2;
    bool huge = ws_size >= 140ull * 1024 * 1024 + headB;
    bool big  = ws_size >= 68ull * 1024 * 1024 + headB;
    bool mid  = ws_size >= 68ull * 1024 * 1024;

    dim3 blk(256);
    dim3 blkA(512);
    embed_kernel<<<dim3(M_TOK), blk, 0, stream>>>(idx, tok, pos, x);

    if (huge) {
        tconv_qkvo_all<<<dim3(16, 16, 16), blk, 0, stream>>>(Wq, Wk, Wv, Wo, wall);
        tconv_w_all<<<dim3(64, 16, 4), blk, 0, stream>>>(W1, w1all, E_DIM, F_DIM);
        tconv_w_all<<<dim3(16, 64, 4), blk, 0, stream>>>(W2, w2all, F_DIM, E_DIM);
        int n = V_DIM * E_DIM;
        conv_kernel<<<dim3((n / 8 + 255) / 256), blk, 0, stream>>>(headW, hdbH, n);

        for (int l = 0; l < L_NUM; ++l) {
            const ushort* wl  = wall  + (size_t)(l * 4) * E_DIM * E_DIM;
            const ushort* wol = wall  + (size_t)(l * 4 + 3) * E_DIM * E_DIM;
            const ushort* w1l = w1all + (size_t)l * E_DIM * F_DIM;
            const ushort* w2l = w2all + (size_t)l * F_DIM * E_DIM;

            ln_kernel<<<dim3(M_TOK), blk, 0, stream>>>(x, ln1w + l * E_DIM, ln1b + l * E_DIM, h);
            gemm64_qkv_kernel<<<dim3(768), blk, 0, stream>>>(h, wl,
                bq + l*E_DIM, bk + l*E_DIM, bv + l*E_DIM, qb, kb, vb);
            attn_mfma_kernel<<<dim3(512), blkA, 0, stream>>>(qb, kb, vb, yb);
            gemm64_kernel<1><<<dim3(256), blk, 0, stream>>>(yb, wol, bo + l*E_DIM, x, x, nullptr, E_DIM, E_DIM);
            ln_kernel<<<dim3(M_TOK), blk, 0, stream>>>(x, ln2w + l * E_DIM, ln2b + l * E_DIM, h);
            gemm_bb_kernel<2><<<dim3(512), blk, 0, stream>>>(h, w1l, b1 + l*F_DIM, nullptr, nullptr, ub, F_DIM, E_DIM, F_DIM);
            gemm64_kernel<1><<<dim3(256), blk, 0, stream>>>(ub, w2l, b2 + l*E_DIM, x, x, nullptr, E_DIM, F_DIM);
        }
        ln_kernel<<<dim3(M_TOK), blk, 0, stream>>>(x, lnfw, lnfb, h);
        gemm_head_kernel<<<dim3(3200), blkA, 0, stream>>>(h, hdbH, out, V_DIM, E_DIM, V_DIM);
        return;
    }

    if (big) {
        int n = V_DIM * E_DIM;
        conv_kernel<<<dim3((n / 8 + 255) / 256), blk, 0, stream>>>(headW, hdbM, n);
    }

    for (int l = 0; l < L_NUM; ++l) {
        const float* wq = Wq + (size_t)l * E_DIM * E_DIM;
        const float* wk = Wk + (size_t)l * E_DIM * E_DIM;
        const float* wv = Wv + (size_t)l * E_DIM * E_DIM;
        const float* wo = Wo + (size_t)l * E_DIM * E_DIM;
        const float* w1 = W1 + (size_t)l * E_DIM * F_DIM;
        const float* w2 = W2 + (size_t)l * F_DIM * E_DIM;

        ln_kernel<<<dim3(M_TOK), blk, 0, stream>>>(x, ln1w + l * E_DIM, ln1b + l * E_DIM, h);
        if (mid) {
            tconv_kernel<<<dim3(16, 16), blk, 0, stream>>>(wq, wqb, E_DIM, E_DIM);
            tconv_kernel<<<dim3(16, 16), blk, 0, stream>>>(wk, wkb, E_DIM, E_DIM);
            tconv_kernel<<<dim3(16, 16), blk, 0, stream>>>(wv, wvb, E_DIM, E_DIM);
            tconv_kernel<<<dim3(16, 16), blk, 0, stream>>>(wo, wob, E_DIM, E_DIM);
            tconv_kernel<<<dim3(64, 16), blk, 0, stream>>>(w1, w1b, E_DIM, F_DIM);
            tconv_kernel<<<dim3(16, 64), blk, 0, stream>>>(w2, w2b, F_DIM, E_DIM);

            gemm_qkv_bb_kernel<<<dim3(384), blk, 0, stream>>>(h, wqb, wkb, wvb,
                bq + l*E_DIM, bk + l*E_DIM, bv + l*E_DIM, qb, kb, vb);
            attn_mfma_kernel<<<dim3(512), blkA, 0, stream>>>(qb, kb, vb, yb);
            gemm_bb_kernel<1><<<dim3(128), blk, 0, stream>>>(yb, wob, bo + l*E_DIM, x, x, nullptr, E_DIM, E_DIM, E_DIM);
            ln_kernel<<<dim3(M_TOK), blk, 0, stream>>>(x, ln2w + l * E_DIM, ln2b + l * E_DIM, h);
            gemm_bb_kernel<2><<<dim3(512), blk, 0, stream>>>(h, w1b, b1 + l*F_DIM, nullptr, nullptr, ub, F_DIM, E_DIM, F_DIM);
            gemm_bb_kernel<1><<<dim3(128), blk, 0, stream>>>(ub, w2b, b2 + l*E_DIM, x, x, nullptr, E_DIM, F_DIM, E_DIM);
        }
    }

    ln_kernel<<<dim3(M_TOK), blk, 0, stream>>>(x, lnfw, lnfb, h);
    if (big) {
        gemm_head_kernel<<<dim3(3200), blkA, 0, stream>>>(h, hdbM, out, V_DIM, E_DIM, V_DIM);
    }
}

// Round 13
// 1151.419 us; speedup vs baseline: 1.0064x; 1.0064x over previous
//
#include <hip/hip_runtime.h>
#include <hip/hip_bf16.h>
#include <math.h>

#define E_DIM 1024
#define H_NUM 16
#define D_DIM 64
#define F_DIM 4096
#define L_NUM 4
#define B_NUM 2
#define S_LEN 1024
#define V_DIM 50257
#define M_TOK 2048   // B*S

typedef __attribute__((ext_vector_type(8))) short s8v;    // 8 bf16 (4 VGPRs)
typedef __attribute__((ext_vector_type(4))) float f4v;    // 4 fp32

static __device__ __forceinline__ float bf2f(unsigned short u) {
    union { unsigned int i; float f; } c; c.i = ((unsigned int)u) << 16; return c.f;
}
static __device__ __forceinline__ unsigned short f2bf(float f) {
    union { float f; unsigned int i; } c; c.f = f;
    unsigned int r = c.i + 0x7FFFu + ((c.i >> 16) & 1u);
    return (unsigned short)(r >> 16);
}

// async global->LDS, 16B per lane; dest is wave-uniform base + lane*16
static __device__ __forceinline__ void gload16(const ushort* g, ushort* l) {
    __builtin_amdgcn_global_load_lds(
        (const __attribute__((address_space(1))) unsigned int*)g,
        (__attribute__((address_space(3))) unsigned int*)l, 16, 0, 0);
}

// ---------------------------------------------------------------- embedding
__global__ void embed_kernel(const int* __restrict__ idx,
                             const float* __restrict__ tok,
                             const float* __restrict__ pos,
                             float* __restrict__ x) {
    int row = blockIdx.x;
    int s = row & (S_LEN - 1);
    int t = idx[row];
    const float* te = tok + (size_t)t * E_DIM;
    const float* pe = pos + (size_t)s * E_DIM;
    float* xr = x + (size_t)row * E_DIM;
    int c = threadIdx.x * 4;
    float4 a = *(const float4*)(te + c);
    float4 p = *(const float4*)(pe + c);
    float4 o; o.x = a.x + p.x; o.y = a.y + p.y; o.z = a.z + p.z; o.w = a.w + p.w;
    *(float4*)(xr + c) = o;
}

// ---------------------------------------------------------------- layernorm
__global__ void ln_kernel(const float* __restrict__ x,
                          const float* __restrict__ w,
                          const float* __restrict__ b,
                          ushort* __restrict__ out) {
    int row = blockIdx.x;
    const float* xr = x + (size_t)row * E_DIM;
    int tid = threadIdx.x;
    float4 v = *(const float4*)(xr + tid * 4);
    float s  = v.x + v.y + v.z + v.w;
    float s2 = v.x*v.x + v.y*v.y + v.z*v.z + v.w*v.w;
    #pragma unroll
    for (int m = 32; m >= 1; m >>= 1) {
        s  += __shfl_xor(s,  m, 64);
        s2 += __shfl_xor(s2, m, 64);
    }
    __shared__ float red[8];
    int wid = tid >> 6;
    if ((tid & 63) == 0) { red[wid] = s; red[wid + 4] = s2; }
    __syncthreads();
    s  = red[0] + red[1] + red[2] + red[3];
    s2 = red[4] + red[5] + red[6] + red[7];
    float mu  = s * (1.0f / E_DIM);
    float var = s2 * (1.0f / E_DIM) - mu * mu;
    float rs  = rsqrtf(var + 1e-5f);
    float4 wv = *(const float4*)(w + tid * 4);
    float4 bv = *(const float4*)(b + tid * 4);
    ushort4 o;
    o.x = f2bf((v.x - mu) * rs * wv.x + bv.x);
    o.y = f2bf((v.y - mu) * rs * wv.y + bv.y);
    o.z = f2bf((v.z - mu) * rs * wv.z + bv.z);
    o.w = f2bf((v.w - mu) * rs * wv.w + bv.w);
    *(ushort4*)(out + (size_t)row * E_DIM + tid * 4) = o;
}

// ---------------------------------------------------------------- weight prep
static __device__ __forceinline__ void tconv_body(
    const float* __restrict__ in, ushort* __restrict__ out, int K, int N, int bx, int by)
{
    __shared__ ushort t[64][72];
    int n0 = bx * 64, k0 = by * 64;
    int tid = threadIdx.x;
    int r = tid >> 4, c = (tid & 15) * 4;
    #pragma unroll
    for (int it = 0; it < 4; ++it) {
        int kl = it * 16 + r;
        float4 v = *(const float4*)(in + (size_t)(k0 + kl) * N + n0 + c);
        t[kl][c]   = f2bf(v.x); t[kl][c+1] = f2bf(v.y);
        t[kl][c+2] = f2bf(v.z); t[kl][c+3] = f2bf(v.w);
    }
    __syncthreads();
    int nl = tid >> 2, k8 = (tid & 3) * 16;
    s8v o0, o1;
    #pragma unroll
    for (int j = 0; j < 8; ++j) o0[j] = (short)t[k8 + j][nl];
    #pragma unroll
    for (int j = 0; j < 8; ++j) o1[j] = (short)t[k8 + 8 + j][nl];
    *(s8v*)(out + (size_t)(n0 + nl) * K + k0 + k8)     = o0;
    *(s8v*)(out + (size_t)(n0 + nl) * K + k0 + k8 + 8) = o1;
}

__global__ __launch_bounds__(256) void tconv_kernel(const float* __restrict__ in,
                                                    ushort* __restrict__ out, int K, int N) {
    tconv_body(in, out, K, N, blockIdx.x, blockIdx.y);
}

__global__ __launch_bounds__(256) void tconv_qkvo_all(
    const float* __restrict__ Wq, const float* __restrict__ Wk,
    const float* __restrict__ Wv, const float* __restrict__ Wo,
    ushort* __restrict__ out)
{
    int z = blockIdx.z, l = z >> 2, w = z & 3;
    const float* in = (w == 0 ? Wq : w == 1 ? Wk : w == 2 ? Wv : Wo)
                      + (size_t)l * E_DIM * E_DIM;
    tconv_body(in, out + (size_t)z * E_DIM * E_DIM, E_DIM, E_DIM, blockIdx.x, blockIdx.y);
}

__global__ __launch_bounds__(256) void tconv_w_all(
    const float* __restrict__ W, ushort* __restrict__ out, int K, int N)
{
    int l = blockIdx.z;
    tconv_body(W + (size_t)l * K * N, out + (size_t)l * K * N, K, N, blockIdx.x, blockIdx.y);
}

__global__ void conv_kernel(const float* __restrict__ in, ushort* __restrict__ out, int n) {
    int i = (blockIdx.x * 256 + threadIdx.x) * 8;
    if (i + 8 <= n) {
        float4 a = *(const float4*)(in + i);
        float4 b = *(const float4*)(in + i + 4);
        s8v o;
        o[0]=(short)f2bf(a.x); o[1]=(short)f2bf(a.y); o[2]=(short)f2bf(a.z); o[3]=(short)f2bf(a.w);
        o[4]=(short)f2bf(b.x); o[5]=(short)f2bf(b.y); o[6]=(short)f2bf(b.z); o[7]=(short)f2bf(b.w);
        *(s8v*)(out + i) = o;
    }
}

// ---------------------------------------------------------------- MFMA flash attention (split-KV)
// qt remap (R10-proven): bid<256 -> qt 15..8, bid>=256 -> qt 0..7.
// CU pairs (bid, bid+256) => (qt, 15-qt): round-sums all equal 9 (was 6..12).
#define KSTR 72
#define VSTR 144
__global__ __launch_bounds__(512, 4) void attn_mfma_kernel(
    const ushort* __restrict__ qg, const ushort* __restrict__ kg,
    const ushort* __restrict__ vg, ushort* __restrict__ yg)
{
    __shared__ ushort smem[27648];
    ushort (*Ks)[KSTR] = (ushort(*)[KSTR])smem;
    ushort (*Vt)[VSTR] = (ushort(*)[VSTR])(smem + 128 * KSTR);
    ushort (*Ps)[16][KSTR] = (ushort(*)[16][KSTR])(smem + 128 * KSTR + 64 * VSTR);
    float* mb = (float*)smem;

    int tid = threadIdx.x;
    int wid = tid >> 6, lane = tid & 63;
    int c = lane & 15, g = lane >> 4;
    int grp = wid >> 2, ws = wid & 3;

    int bid = blockIdx.x;
    int head = bid & 31;
    int qt = (bid < 256) ? (15 - (bid >> 5)) : ((bid >> 5) - 8);
    int b = head >> 4, h = head & 15;
    int qw = qt * 64 + ws * 16;
    size_t base = (size_t)b * S_LEN * E_DIM + (size_t)(h * D_DIM);

    s8v qf[2];
    #pragma unroll
    for (int ks = 0; ks < 2; ++ks)
        qf[ks] = *(const s8v*)(qg + base + (size_t)(qw + c) * E_DIM + ks * 32 + g * 8);

    f4v o[4];
    #pragma unroll
    for (int dt = 0; dt < 4; ++dt) o[dt] = (f4v){0.f, 0.f, 0.f, 0.f};
    float m[4], lsum[4];
    #pragma unroll
    for (int j = 0; j < 4; ++j) { m[j] = -1e30f; lsum[j] = 0.f; }

    int nr = (qt >> 1) + 1;
    for (int r = 0; r < nr; ++r) {
        int t0 = r * 128;
        #pragma unroll
        for (int it = 0; it < 2; ++it) {
            int ch = tid + it * 512;
            int tr = ch >> 3, dc = (ch & 7) << 3;
            s8v kv = *(const s8v*)(kg + base + (size_t)(t0 + tr) * E_DIM + dc);
            *(s8v*)(&Ks[tr][dc]) = kv;
            s8v vv = *(const s8v*)(vg + base + (size_t)(t0 + tr) * E_DIM + dc);
            int tsw = tr ^ dc;
            #pragma unroll
            for (int j = 0; j < 8; ++j)
                Vt[dc + j][tsw] = (ushort)vv[j];
        }
        __syncthreads();

        int myt = r * 2 + grp;
        if (myt <= qt) {
            int toff = grp * 64;
            f4v s4[4];
            #pragma unroll
            for (int tj = 0; tj < 4; ++tj) {
                s4[tj] = (f4v){0.f, 0.f, 0.f, 0.f};
                #pragma unroll
                for (int ks = 0; ks < 2; ++ks) {
                    s8v kf = *(const s8v*)(&Ks[toff + tj * 16 + c][ks * 32 + g * 8]);
                    s4[tj] = __builtin_amdgcn_mfma_f32_16x16x32_bf16(qf[ks], kf, s4[tj], 0, 0, 0);
                }
            }

            bool diag = (myt == qt);
            float sc[4][4], pm[4];
            #pragma unroll
            for (int j = 0; j < 4; ++j) pm[j] = -1e30f;
            #pragma unroll
            for (int tj = 0; tj < 4; ++tj)
                #pragma unroll
                for (int j = 0; j < 4; ++j) {
                    float val = s4[tj][j] * 0.125f;
                    if (diag) {
                        int t_loc = tj * 16 + c;
                        int q_loc = ws * 16 + 4 * g + j;
                        if (t_loc > q_loc) val = -1e30f;
                    }
                    sc[tj][j] = val;
                    pm[j] = fmaxf(pm[j], val);
                }
            #pragma unroll
            for (int msk = 1; msk <= 8; msk <<= 1)
                #pragma unroll
                for (int j = 0; j < 4; ++j)
                    pm[j] = fmaxf(pm[j], __shfl_xor(pm[j], msk, 64));
            float rs[4], corr[4];
            #pragma unroll
            for (int j = 0; j < 4; ++j) {
                float nm = fmaxf(m[j], pm[j]);
                corr[j] = __expf(m[j] - nm);
                m[j] = nm;
                rs[j] = 0.f;
            }
            #pragma unroll
            for (int tj = 0; tj < 4; ++tj)
                #pragma unroll
                for (int j = 0; j < 4; ++j) {
                    float p = __expf(sc[tj][j] - m[j]);
                    rs[j] += p;
                    Ps[wid][4 * g + j][(tj * 16 + c) ^ (g << 3)] = f2bf(p);
                }
            #pragma unroll
            for (int msk = 1; msk <= 8; msk <<= 1)
                #pragma unroll
                for (int j = 0; j < 4; ++j)
                    rs[j] += __shfl_xor(rs[j], msk, 64);
            #pragma unroll
            for (int j = 0; j < 4; ++j) lsum[j] = lsum[j] * corr[j] + rs[j];
            #pragma unroll
            for (int dt = 0; dt < 4; ++dt)
                #pragma unroll
                for (int j = 0; j < 4; ++j) o[dt][j] *= corr[j];

            #pragma unroll
            for (int ks = 0; ks < 2; ++ks) {
                int blk = g + 4 * ks;
                int pblk = blk ^ (c >> 2);
                s8v pa = *(const s8v*)(&Ps[wid][c][pblk << 3]);
                int tb = grp * 8 + blk;
                #pragma unroll
                for (int dt = 0; dt < 4; ++dt) {
                    int d = dt * 16 + c;
                    int vblk = tb ^ ((d >> 3) & 7);
                    s8v vb = *(const s8v*)(&Vt[d][vblk << 3]);
                    o[dt] = __builtin_amdgcn_mfma_f32_16x16x32_bf16(pa, vb, o[dt], 0, 0, 0);
                }
            }
        }
        __syncthreads();
    }

    if (grp == 1) {
        float* dst = mb + (ws * 64 + lane) * 25;
        #pragma unroll
        for (int j = 0; j < 4; ++j) { dst[j] = m[j]; dst[4 + j] = lsum[j]; }
        #pragma unroll
        for (int dt = 0; dt < 4; ++dt)
            #pragma unroll
            for (int j = 0; j < 4; ++j) dst[8 + dt * 4 + j] = o[dt][j];
    }
    __syncthreads();
    if (grp == 0) {
        const float* src = mb + (ws * 64 + lane) * 25;
        float sA[4], sB[4];
        #pragma unroll
        for (int j = 0; j < 4; ++j) {
            float mB = src[j], lB = src[4 + j];
            float mN = fmaxf(m[j], mB);
            sA[j] = __expf(m[j] - mN);
            sB[j] = __expf(mB - mN);
            lsum[j] = lsum[j] * sA[j] + lB * sB[j];
        }
        float inv[4];
        #pragma unroll
        for (int j = 0; j < 4; ++j) inv[j] = 1.f / lsum[j];
        #pragma unroll
        for (int dt = 0; dt < 4; ++dt)
            #pragma unroll
            for (int j = 0; j < 4; ++j) {
                float ov = o[dt][j] * sA[j] + src[8 + dt * 4 + j] * sB[j];
                yg[base + (size_t)(qw + 4 * g + j) * E_DIM + dt * 16 + c] = f2bf(ov * inv[j]);
            }
    }
}

// ---------------------------------------------------------------- bf16 GEMM 128x128 (proven)
template<int EPI>
static __device__ __forceinline__ void gemm_bb_body(
    const ushort* __restrict__ A, const ushort* __restrict__ B,
    const float* __restrict__ bias, const float* __restrict__ res,
    float* __restrict__ outF, ushort* __restrict__ outB,
    int Ndim, int Kdim, int m0, int n0, int nRows)
{
    __shared__ ushort As[128 * 64];
    __shared__ ushort Bs[128 * 64];
    int tid = threadIdx.x;
    int wid = tid >> 6, lane = tid & 63;
    int wr = wid >> 1, wc = wid & 1;
    int fr = lane & 15, fq = lane >> 4;
    int lr = lane >> 3, ls = lane & 7;

    f4v acc[4][4];
    #pragma unroll
    for (int mi = 0; mi < 4; ++mi)
        #pragma unroll
        for (int ni = 0; ni < 4; ++ni)
            acc[mi][ni] = (f4v){0.f, 0.f, 0.f, 0.f};

    for (int k0 = 0; k0 < Kdim; k0 += 64) {
        #pragma unroll
        for (int it = 0; it < 4; ++it) {
            int r = wid * 32 + it * 8 + lr;
            int ss = ls ^ (r & 7);
            gload16(A + (size_t)(m0 + r) * Kdim + k0 + ss * 8,
                    As + r * 64 - lr * 64 - ls * 8);
        }
        #pragma unroll
        for (int it = 0; it < 4; ++it) {
            int r = wid * 32 + it * 8 + lr;
            int ss = ls ^ (r & 7);
            int br = n0 + r; if (br >= nRows) br = nRows - 1;
            gload16(B + (size_t)br * Kdim + k0 + ss * 8,
                    Bs + r * 64 - lr * 64 - ls * 8);
        }
        __syncthreads();
        #pragma unroll
        for (int ks = 0; ks < 2; ++ks) {
            s8v af[4], bfv[4];
            #pragma unroll
            for (int mi = 0; mi < 4; ++mi) {
                int Ra = wr * 64 + mi * 16 + fr;
                int Sa = (ks * 4 + fq) ^ (fr & 7);
                af[mi] = *(const s8v*)(As + Ra * 64 + Sa * 8);
            }
            #pragma unroll
            for (int ni = 0; ni < 4; ++ni) {
                int Rb = wc * 64 + ni * 16 + fr;
                int Sb = (ks * 4 + fq) ^ (fr & 7);
                bfv[ni] = *(const s8v*)(Bs + Rb * 64 + Sb * 8);
            }
            #pragma unroll
            for (int mi = 0; mi < 4; ++mi)
                #pragma unroll
                for (int ni = 0; ni < 4; ++ni)
                    acc[mi][ni] = __builtin_amdgcn_mfma_f32_16x16x32_bf16(
                        af[mi], bfv[ni], acc[mi][ni], 0, 0, 0);
        }
        __syncthreads();
    }

    #pragma unroll
    for (int mi = 0; mi < 4; ++mi) {
        int row = m0 + wr * 64 + mi * 16 + fq * 4;
        #pragma unroll
        for (int ni = 0; ni < 4; ++ni) {
            int col = n0 + wc * 64 + ni * 16 + fr;
            float bv = 0.f;
            if (EPI == 0 || EPI == 1 || EPI == 2) bv = bias[col];
            #pragma unroll
            for (int j = 0; j < 4; ++j) {
                float val = acc[mi][ni][j] + bv;
                size_t off = (size_t)(row + j) * Ndim + col;
                if (EPI == 0) {
                    outB[off] = f2bf(val);
                } else if (EPI == 1) {
                    outF[off] = res[off] + val;
                } else if (EPI == 2) {
                    val = 0.5f * val * (1.f + erff(val * 0.70710678118654752f));
                    outB[off] = f2bf(val);
                } else {
                    if (col < Ndim) outF[off] = val;
                }
            }
        }
    }
}

template<int EPI>
__global__ __launch_bounds__(256) void gemm_bb_kernel(
    const ushort* __restrict__ A, const ushort* __restrict__ B,
    const float* __restrict__ bias, const float* __restrict__ res,
    float* __restrict__ outF, ushort* __restrict__ outB,
    int Ndim, int Kdim, int nRows)
{
    int x = blockIdx.x & 7, i = blockIdx.x >> 3;
    int mb = x * 2 + (i & 1), nb = i >> 1;
    gemm_bb_body<EPI>(A, B, bias, res, outF, outB, Ndim, Kdim, mb * 128, nb * 128, nRows);
}

__global__ __launch_bounds__(256) void gemm_qkv_bb_kernel(
    const ushort* __restrict__ A,
    const ushort* __restrict__ Bq, const ushort* __restrict__ Bk, const ushort* __restrict__ Bv,
    const float* __restrict__ bq, const float* __restrict__ bk, const float* __restrict__ bv,
    ushort* __restrict__ oq, ushort* __restrict__ ok, ushort* __restrict__ ov)
{
    int x = blockIdx.x & 7, i = blockIdx.x >> 3;
    int sel = i >> 4, j = i & 15;
    int mb = x * 2 + (j & 1), nb = j >> 1;
    const ushort* B   = (sel == 0) ? Bq : (sel == 1) ? Bk : Bv;
    const float* bias = (sel == 0) ? bq : (sel == 1) ? bk : bv;
    ushort* o         = (sel == 0) ? oq : (sel == 1) ? ok : ov;
    gemm_bb_body<0>(A, B, bias, nullptr, nullptr, o, E_DIM, E_DIM, mb * 128, nb * 128, E_DIM);
}

// ---------------------------------------------------------------- bf16 GEMM 64x128
template<int EPI>
static __device__ __forceinline__ void gemm64_body(
    const ushort* __restrict__ A, const ushort* __restrict__ B,
    const float* __restrict__ bias, const float* __restrict__ res,
    float* __restrict__ outF, ushort* __restrict__ outB,
    int Ndim, int Kdim, int m0, int n0)
{
    __shared__ ushort As[64 * 64];
    __shared__ ushort Bs[128 * 64];
    int tid = threadIdx.x;
    int wid = tid >> 6, lane = tid & 63;
    int fr = lane & 15, fq = lane >> 4;
    int lr = lane >> 3, ls = lane & 7;

    f4v acc[4][2];
    #pragma unroll
    for (int mi = 0; mi < 4; ++mi)
        #pragma unroll
        for (int ni = 0; ni < 2; ++ni)
            acc[mi][ni] = (f4v){0.f, 0.f, 0.f, 0.f};

    for (int k0 = 0; k0 < Kdim; k0 += 64) {
        #pragma unroll
        for (int it = 0; it < 2; ++it) {
            int r = wid * 16 + it * 8 + lr;
            int ss = ls ^ (r & 7);
            gload16(A + (size_t)(m0 + r) * Kdim + k0 + ss * 8,
                    As + r * 64 - lr * 64 - ls * 8);
        }
        #pragma unroll
        for (int it = 0; it < 4; ++it) {
            int r = wid * 32 + it * 8 + lr;
            int ss = ls ^ (r & 7);
            gload16(B + (size_t)(n0 + r) * Kdim + k0 + ss * 8,
                    Bs + r * 64 - lr * 64 - ls * 8);
        }
        __syncthreads();
        #pragma unroll
        for (int ks = 0; ks < 2; ++ks) {
            s8v af[4], bfv[2];
            #pragma unroll
            for (int mi = 0; mi < 4; ++mi) {
                int Ra = mi * 16 + fr;
                int Sa = (ks * 4 + fq) ^ (fr & 7);
                af[mi] = *(const s8v*)(As + Ra * 64 + Sa * 8);
            }
            #pragma unroll
            for (int ni = 0; ni < 2; ++ni) {
                int Rb = wid * 32 + ni * 16 + fr;
                int Sb = (ks * 4 + fq) ^ (fr & 7);
                bfv[ni] = *(const s8v*)(Bs + Rb * 64 + Sb * 8);
            }
            #pragma unroll
            for (int mi = 0; mi < 4; ++mi)
                #pragma unroll
                for (int ni = 0; ni < 2; ++ni)
                    acc[mi][ni] = __builtin_amdgcn_mfma_f32_16x16x32_bf16(
                        af[mi], bfv[ni], acc[mi][ni], 0, 0, 0);
        }
        __syncthreads();
    }

    #pragma unroll
    for (int mi = 0; mi < 4; ++mi) {
        int row = m0 + mi * 16 + fq * 4;
        #pragma unroll
        for (int ni = 0; ni < 2; ++ni) {
            int col = n0 + wid * 32 + ni * 16 + fr;
            float bv = bias[col];
            #pragma unroll
            for (int j = 0; j < 4; ++j) {
                float val = acc[mi][ni][j] + bv;
                size_t off = (size_t)(row + j) * Ndim + col;
                if (EPI == 0) {
                    outB[off] = f2bf(val);
                } else {
                    outF[off] = res[off] + val;
                }
            }
        }
    }
}

template<int EPI>
__global__ __launch_bounds__(256) void gemm64_kernel(
    const ushort* __restrict__ A, const ushort* __restrict__ B,
    const float* __restrict__ bias, const float* __restrict__ res,
    float* __restrict__ outF, ushort* __restrict__ outB,
    int Ndim, int Kdim)
{
    int x = blockIdx.x & 7, i = blockIdx.x >> 3;
    int mb = x * 4 + (i & 3), nb = i >> 2;
    gemm64_body<EPI>(A, B, bias, res, outF, outB, Ndim, Kdim, mb * 64, nb * 128);
}

__global__ __launch_bounds__(256) void gemm64_qkv_kernel(
    const ushort* __restrict__ A, const ushort* __restrict__ Wall,
    const float* __restrict__ bq, const float* __restrict__ bk, const float* __restrict__ bv,
    ushort* __restrict__ oq, ushort* __restrict__ ok, ushort* __restrict__ ov)
{
    int x = blockIdx.x & 7, i = blockIdx.x >> 3;
    int sel = i >> 5, j = i & 31;
    int mb = x * 4 + (j & 3), nb = j >> 2;
    const ushort* B   = Wall + (size_t)sel * E_DIM * E_DIM;
    const float* bias = (sel == 0) ? bq : (sel == 1) ? bk : bv;
    ushort* o         = (sel == 0) ? oq : (sel == 1) ? ok : ov;
    gemm64_body<0>(A, B, bias, nullptr, nullptr, o, E_DIM, E_DIM, mb * 64, nb * 128);
}

// ---------------------------------------------------------------- head GEMM 256x128, 8 waves
// R9/R11-proven configuration (285us, MfmaUtil 31%, 0 conflicts): mb = bid&7 (= XCD,
// A slice L2-resident), nb = bid>>3, grid 3144, plain fp32 stores.
// R12's nb-sliced mapping cut FETCH 417->180MB with NO speedup -> head is
// structure-bound, not memory-bound; traffic shaping is exhausted.
__global__ __launch_bounds__(512) void gemm_head_kernel(
    const ushort* __restrict__ A, const ushort* __restrict__ B,
    float* __restrict__ outF, int Ndim, int Kdim, int nRows)
{
    __shared__ ushort As[256 * 64];
    __shared__ ushort Bs[128 * 64];
    int tid = threadIdx.x;
    int wid = tid >> 6, lane = tid & 63;
    int wr = wid >> 1, wc = wid & 1;         // 4M x 2N wave grid
    int fr = lane & 15, fq = lane >> 4;
    int lr = lane >> 3, ls = lane & 7;

    int mb = blockIdx.x & 7, nb = blockIdx.x >> 3;
    int m0 = mb * 256, n0 = nb * 128;

    f4v acc[4][4];
    #pragma unroll
    for (int mi = 0; mi < 4; ++mi)
        #pragma unroll
        for (int ni = 0; ni < 4; ++ni)
            acc[mi][ni] = (f4v){0.f, 0.f, 0.f, 0.f};

    for (int k0 = 0; k0 < Kdim; k0 += 64) {
        #pragma unroll
        for (int it = 0; it < 4; ++it) {
            int r = wid * 32 + it * 8 + lr;
            int ss = ls ^ (r & 7);
            gload16(A + (size_t)(m0 + r) * Kdim + k0 + ss * 8,
                    As + r * 64 - lr * 64 - ls * 8);
        }
        #pragma unroll
        for (int it = 0; it < 2; ++it) {
            int r = wid * 16 + it * 8 + lr;
            int ss = ls ^ (r & 7);
            int br = n0 + r; if (br >= nRows) br = nRows - 1;
            gload16(B + (size_t)br * Kdim + k0 + ss * 8,
                    Bs + r * 64 - lr * 64 - ls * 8);
        }
        __syncthreads();
        #pragma unroll
        for (int ks = 0; ks < 2; ++ks) {
            s8v af[4], bfv[4];
            #pragma unroll
            for (int mi = 0; mi < 4; ++mi) {
                int Ra = wr * 64 + mi * 16 + fr;
                int Sa = (ks * 4 + fq) ^ (fr & 7);
                af[mi] = *(const s8v*)(As + Ra * 64 + Sa * 8);
            }
            #pragma unroll
            for (int ni = 0; ni < 4; ++ni) {
                int Rb = wc * 64 + ni * 16 + fr;
                int Sb = (ks * 4 + fq) ^ (fr & 7);
                bfv[ni] = *(const s8v*)(Bs + Rb * 64 + Sb * 8);
            }
            #pragma unroll
            for (int mi = 0; mi < 4; ++mi)
                #pragma unroll
                for (int ni = 0; ni < 4; ++ni)
                    acc[mi][ni] = __builtin_amdgcn_mfma_f32_16x16x32_bf16(
                        af[mi], bfv[ni], acc[mi][ni], 0, 0, 0);
        }
        __syncthreads();
    }

    #pragma unroll
    for (int mi = 0; mi < 4; ++mi) {
        int row = m0 + wr * 64 + mi * 16 + fq * 4;
        #pragma unroll
        for (int ni = 0; ni < 4; ++ni) {
            int col = n0 + wc * 64 + ni * 16 + fr;
            if (col < Ndim) {
                #pragma unroll
                for (int j = 0; j < 4; ++j)
                    outF[(size_t)(row + j) * Ndim + col] = acc[mi][ni][j];
            }
        }
    }
}

// ---------------------------------------------------------------- launch
extern "C" void kernel_launch(void* const* d_in, const int* in_sizes, int n_in,
                              void* d_out, int out_size, void* d_ws, size_t ws_size,
                              hipStream_t stream) {
    (void)in_sizes; (void)n_in; (void)out_size;
    const int*   idx  = (const int*)d_in[0];
    const float* tok  = (const float*)d_in[1];
    const float* pos  = (const float*)d_in[2];
    const float* ln1w = (const float*)d_in[3];
    const float* ln1b = (const float*)d_in[4];
    const float* Wq   = (const float*)d_in[5];
    const float* bq   = (const float*)d_in[6];
    const float* Wk   = (const float*)d_in[7];
    const float* bk   = (const float*)d_in[8];
    const float* Wv   = (const float*)d_in[9];
    const float* bv   = (const float*)d_in[10];
    const float* Wo   = (const float*)d_in[11];
    const float* bo   = (const float*)d_in[12];
    const float* ln2w = (const float*)d_in[13];
    const float* ln2b = (const float*)d_in[14];
    const float* W1   = (const float*)d_in[15];
    const float* b1   = (const float*)d_in[16];
    const float* W2   = (const float*)d_in[17];
    const float* b2   = (const float*)d_in[18];
    const float* lnfw = (const float*)d_in[19];
    const float* lnfb = (const float*)d_in[20];
    const float* headW= (const float*)d_in[21];
    float* out = (float*)d_out;

    char* ws = (char*)d_ws;
    float*  x  = (float*)(ws);                              // 8 MB
    ushort* h  = (ushort*)(ws + 8u  * 1024 * 1024);         // 4 MB
    ushort* qb = (ushort*)(ws + 12u * 1024 * 1024);
    ushort* kb = (ushort*)(ws + 16u * 1024 * 1024);
    ushort* vb = (ushort*)(ws + 20u * 1024 * 1024);
    ushort* yb = (ushort*)(ws + 24u * 1024 * 1024);
    ushort* ub = (ushort*)(ws + 28u * 1024 * 1024);         // 16 MB
    // mid tier: per-layer reuse buffers
    ushort* wqb = (ushort*)(ws + 44u * 1024 * 1024);
    ushort* wkb = (ushort*)(ws + 46u * 1024 * 1024);
    ushort* wvb = (ushort*)(ws + 48u * 1024 * 1024);
    ushort* wob = (ushort*)(ws + 50u * 1024 * 1024);
    ushort* w1b = (ushort*)(ws + 52u * 1024 * 1024);
    ushort* w2b = (ushort*)(ws + 60u * 1024 * 1024);
    ushort* hdbM = (ushort*)(ws + 68u * 1024 * 1024);       // mid-tier head (98.2 MB)
    // huge tier: all weights upfront
    ushort* wall  = (ushort*)(ws + 44u  * 1024 * 1024);     // 32 MB
    ushort* w1all = (ushort*)(ws + 76u  * 1024 * 1024);     // 32 MB
    ushort* w2all = (ushort*)(ws + 108u * 1024 * 1024);     // 32 MB
    ushort* hdbH  = (ushort*)(ws + 140u * 1024 * 1024);     // 98.2 MB

    size_t headB = (size_t)V_DIM * E_DIM * 2;
    bool huge = ws_size >= 140ull * 1024 * 1024 + headB;
    bool big  = ws_size >= 68ull * 1024 * 1024 + headB;
    bool mid  = ws_size >= 68ull * 1024 * 1024;

    dim3 blk(256);
    dim3 blkA(512);
    embed_kernel<<<dim3(M_TOK), blk, 0, stream>>>(idx, tok, pos, x);

    if (huge) {
        tconv_qkvo_all<<<dim3(16, 16, 16), blk, 0, stream>>>(Wq, Wk, Wv, Wo, wall);
        tconv_w_all<<<dim3(64, 16, 4), blk, 0, stream>>>(W1, w1all, E_DIM, F_DIM);
        tconv_w_all<<<dim3(16, 64, 4), blk, 0, stream>>>(W2, w2all, F_DIM, E_DIM);
        int n = V_DIM * E_DIM;
        conv_kernel<<<dim3((n / 8 + 255) / 256), blk, 0, stream>>>(headW, hdbH, n);

        for (int l = 0; l < L_NUM; ++l) {
            const ushort* wl  = wall  + (size_t)(l * 4) * E_DIM * E_DIM;
            const ushort* wol = wall  + (size_t)(l * 4 + 3) * E_DIM * E_DIM;
            const ushort* w1l = w1all + (size_t)l * E_DIM * F_DIM;
            const ushort* w2l = w2all + (size_t)l * F_DIM * E_DIM;

            ln_kernel<<<dim3(M_TOK), blk, 0, stream>>>(x, ln1w + l * E_DIM, ln1b + l * E_DIM, h);
            gemm64_qkv_kernel<<<dim3(768), blk, 0, stream>>>(h, wl,
                bq + l*E_DIM, bk + l*E_DIM, bv + l*E_DIM, qb, kb, vb);
            attn_mfma_kernel<<<dim3(512), blkA, 0, stream>>>(qb, kb, vb, yb);
            gemm64_kernel<1><<<dim3(256), blk, 0, stream>>>(yb, wol, bo + l*E_DIM, x, x, nullptr, E_DIM, E_DIM);
            ln_kernel<<<dim3(M_TOK), blk, 0, stream>>>(x, ln2w + l * E_DIM, ln2b + l * E_DIM, h);
            gemm_bb_kernel<2><<<dim3(512), blk, 0, stream>>>(h, w1l, b1 + l*F_DIM, nullptr, nullptr, ub, F_DIM, E_DIM, F_DIM);
            gemm64_kernel<1><<<dim3(256), blk, 0, stream>>>(ub, w2l, b2 + l*E_DIM, x, x, nullptr, E_DIM, F_DIM);
        }
        ln_kernel<<<dim3(M_TOK), blk, 0, stream>>>(x, lnfw, lnfb, h);
        gemm_head_kernel<<<dim3(3144), blkA, 0, stream>>>(h, hdbH, out, V_DIM, E_DIM, V_DIM);
        return;
    }

    if (big) {
        int n = V_DIM * E_DIM;
        conv_kernel<<<dim3((n / 8 + 255) / 256), blk, 0, stream>>>(headW, hdbM, n);
    }

    for (int l = 0; l < L_NUM; ++l) {
        const float* wq = Wq + (size_t)l * E_DIM * E_DIM;
        const float* wk = Wk + (size_t)l * E_DIM * E_DIM;
        const float* wv = Wv + (size_t)l * E_DIM * E_DIM;
        const float* wo = Wo + (size_t)l * E_DIM * E_DIM;
        const float* w1 = W1 + (size_t)l * E_DIM * F_DIM;
        const float* w2 = W2 + (size_t)l * F_DIM * E_DIM;

        ln_kernel<<<dim3(M_TOK), blk, 0, stream>>>(x, ln1w + l * E_DIM, ln1b + l * E_DIM, h);
        if (mid) {
            tconv_kernel<<<dim3(16, 16), blk, 0, stream>>>(wq, wqb, E_DIM, E_DIM);
            tconv_kernel<<<dim3(16, 16), blk, 0, stream>>>(wk, wkb, E_DIM, E_DIM);
            tconv_kernel<<<dim3(16, 16), blk, 0, stream>>>(wv, wvb, E_DIM, E_DIM);
            tconv_kernel<<<dim3(16, 16), blk, 0, stream>>>(wo, wob, E_DIM, E_DIM);
            tconv_kernel<<<dim3(64, 16), blk, 0, stream>>>(w1, w1b, E_DIM, F_DIM);
            tconv_kernel<<<dim3(16, 64), blk, 0, stream>>>(w2, w2b, F_DIM, E_DIM);

            gemm_qkv_bb_kernel<<<dim3(384), blk, 0, stream>>>(h, wqb, wkb, wvb,
                bq + l*E_DIM, bk + l*E_DIM, bv + l*E_DIM, qb, kb, vb);
            attn_mfma_kernel<<<dim3(512), blkA, 0, stream>>>(qb, kb, vb, yb);
            gemm_bb_kernel<1><<<dim3(128), blk, 0, stream>>>(yb, wob, bo + l*E_DIM, x, x, nullptr, E_DIM, E_DIM, E_DIM);
            ln_kernel<<<dim3(M_TOK), blk, 0, stream>>>(x, ln2w + l * E_DIM, ln2b + l * E_DIM, h);
            gemm_bb_kernel<2><<<dim3(512), blk, 0, stream>>>(h, w1b, b1 + l*F_DIM, nullptr, nullptr, ub, F_DIM, E_DIM, F_DIM);
            gemm_bb_kernel<1><<<dim3(128), blk, 0, stream>>>(ub, w2b, b2 + l*E_DIM, x, x, nullptr, E_DIM, F_DIM, E_DIM);
        }
    }

    ln_kernel<<<dim3(M_TOK), blk, 0, stream>>>(x, lnfw, lnfb, h);
    if (big) {
        gemm_head_kernel<<<dim3(3144), blkA, 0, stream>>>(h, hdbM, out, V_DIM, E_DIM, V_DIM);
    }
}